// Round 6
// baseline (2548.470 us; speedup 1.0000x reference)
//
#include <hip/hip_runtime.h>

// MACE interaction: N=50000 nodes, E=800000 edges, C=64, R=8, H=64
// ws layout (floats) — ~102.4 MB + 21 KB (known-safe footprint):
//   xt  : N*256   x' after pre-transform, [n*256 + t*64 + c], t=0:x0', t=1..3:x1'[:,m]
//   agg : N*256   scatter target, same layout
//   W1t : 512     W1t[k*8+r]  = W1[r*64+k]
//   W2t : 4096    W2t[j*64+k] = W2[k*64+j]
//   W3t : 16384   W3t[o*64+k] = W3[k*256+o]

#define FDIM 256

__device__ __forceinline__ float silu_f(float x) {
    return x / (1.0f + __expf(-x));
}

// ---------------- weight transposes (trivial) --------------------------------
__global__ void __launch_bounds__(256) transpose_w(
    const float* __restrict__ W1, const float* __restrict__ W2,
    const float* __restrict__ W3, float* __restrict__ W1t,
    float* __restrict__ W2t, float* __restrict__ W3t)
{
    int i = blockIdx.x * 256 + threadIdx.x;
    if (i < 512)   { int r = i >> 6, k = i & 63;  W1t[k * 8 + r]  = W1[i]; }
    if (i < 4096)  { int k = i >> 6, j = i & 63;  W2t[j * 64 + k] = W2[i]; }
    if (i < 16384) { int k = i >> 8, o = i & 255; W3t[o * 64 + k] = W3[i]; }
}

// ---------------- pre transform: x0 = nf@W0/8 ; x1[:,m] = x1m@W1/8 -----------
__global__ void __launch_bounds__(256) pre_kernel(
    const float* __restrict__ nf, const float* __restrict__ W0,
    const float* __restrict__ W1, float* __restrict__ xt, int nNodes)
{
    const int lane = threadIdx.x & 63;
    const int wave = threadIdx.x >> 6;
    const int waveId = blockIdx.x * 4 + wave;
    const int nWaves = gridDim.x * 4;

    float w0r[64], w1r[64];
#pragma unroll
    for (int c = 0; c < 64; ++c) {
        w0r[c] = W0[c * 64 + lane];
        w1r[c] = W1[c * 64 + lane];
    }

    for (int n = waveId; n < nNodes; n += nWaves) {
        const float* __restrict__ row = nf + (size_t)n * FDIM;
        float a0 = 0.f, a1 = 0.f, a2 = 0.f, a3 = 0.f;
#pragma unroll
        for (int c = 0; c < 64; ++c) {
            float x0  = row[c];
            float xm0 = row[64 + 3 * c + 0];
            float xm1 = row[64 + 3 * c + 1];
            float xm2 = row[64 + 3 * c + 2];
            a0 = fmaf(x0,  w0r[c], a0);
            a1 = fmaf(xm0, w1r[c], a1);
            a2 = fmaf(xm1, w1r[c], a2);
            a3 = fmaf(xm2, w1r[c], a3);
        }
        float* o = xt + (size_t)n * FDIM;
        o[lane]       = a0 * 0.125f;
        o[64 + lane]  = a1 * 0.125f;
        o[128 + lane] = a2 * 0.125f;
        o[192 + lane] = a3 * 0.125f;
    }
}

// ---------------- fused edge kernel: MLP + message + coalesced atomic scatter -
// lane-per-edge compute (uniform s_load weights), wave-private LDS transpose
// for the coalesced scatter. KEY ORDERING (vmcnt is an IN-ORDER counter):
// gather for chunk cb+1 is issued BEFORE the atomics of chunk cb, so the
// vmcnt wait at msg(cb+1) only drains the (oldest) gather loads — the 32
// younger atomics stay in flight and retire under the next 2048-FMA block.
__global__ void __launch_bounds__(256) edge_kernel(
    const float* __restrict__ xt, const float* __restrict__ sph,
    const float* __restrict__ rb, const int* __restrict__ ei,
    const float* __restrict__ W1t, const float* __restrict__ W2t,
    const float* __restrict__ W3t, float* __restrict__ agg, int E)
{
    const int tid  = threadIdx.x;
    const int lane = tid & 63;
    const int wave = tid >> 6;
    const int eBlockBase = blockIdx.x * 256;
    const int e = eBlockBase + tid;
    const int eSafe = (e < E) ? e : (E - 1);

    __shared__ float msgL[4][64][33];   // wave-private 64 edges x 32 floats (+pad)
    __shared__ int   recvL[4][64];

    // ---- layer 1: h1 = silu(rb @ W1) ----
    const float4 rq0 = *reinterpret_cast<const float4*>(rb + (size_t)eSafe * 8);
    const float4 rq1 = *reinterpret_cast<const float4*>(rb + (size_t)eSafe * 8 + 4);
    const float rbv[8] = {rq0.x, rq0.y, rq0.z, rq0.w, rq1.x, rq1.y, rq1.z, rq1.w};

    float h1[64];
#pragma unroll
    for (int k = 0; k < 64; ++k) {
        float acc = 0.f;
#pragma unroll
        for (int r = 0; r < 8; ++r) acc = fmaf(rbv[r], W1t[k * 8 + r], acc);
        h1[k] = silu_f(acc);
    }

    // ---- layer 2: h2 = silu(h1 @ W2) ----
    float h2[64];
#pragma unroll
    for (int j = 0; j < 64; ++j) {
        const float* __restrict__ col = W2t + j * 64;  // wave-uniform -> s_load
        float acc = 0.f;
#pragma unroll
        for (int k = 0; k < 64; ++k) acc = fmaf(h1[k], col[k], acc);
        h2[j] = silu_f(acc);
    }

    const float4 sh = *reinterpret_cast<const float4*>(sph + (size_t)eSafe * 4);
    const float sh1a[3] = {sh.y, sh.z, sh.w};
    const int recv = ei[eSafe];
    const int send = ei[E + eSafe];
    const float* __restrict__ xrow = xt + (size_t)send * FDIM;

    recvL[wave][lane] = recv;

    const float INV_SQRT2 = 0.7071067811865476f;
    const float INV_SQRT3 = 0.5773502691896258f;

    // scatter-phase constants (fixed across chunks)
    const int jj  = lane & 31;
    const int tt  = jj >> 3;
    const int ci2 = jj & 7;
    const int sub = lane >> 5;
    float* const aggScat = agg + tt * 64 + ci2;

    // ---- prologue: gather chunk 0 ----
    float xj0[8], xj1m[3][8];
#pragma unroll
    for (int q = 0; q < 2; ++q) {
        float4 v0 = *reinterpret_cast<const float4*>(xrow + 4 * q);
        xj0[4 * q + 0] = v0.x; xj0[4 * q + 1] = v0.y;
        xj0[4 * q + 2] = v0.z; xj0[4 * q + 3] = v0.w;
#pragma unroll
        for (int m = 0; m < 3; ++m) {
            float4 v1 = *reinterpret_cast<const float4*>(xrow + (m + 1) * 64 + 4 * q);
            xj1m[m][4 * q + 0] = v1.x; xj1m[m][4 * q + 1] = v1.y;
            xj1m[m][4 * q + 2] = v1.z; xj1m[m][4 * q + 3] = v1.w;
        }
    }

    for (int cb = 0; cb < 8; ++cb) {
        // ---- A: layer 3 for this chunk (pure SGPR-stream FMAs) ----
        float wv[4][8];
#pragma unroll
        for (int t = 0; t < 4; ++t) {
#pragma unroll
            for (int ci = 0; ci < 8; ++ci) {
                const float* __restrict__ col =
                    W3t + (size_t)(t * 64 + cb * 8 + ci) * 64;  // uniform -> s_load
                float acc = 0.f;
#pragma unroll
                for (int k = 0; k < 64; ++k) acc = fmaf(h2[k], col[k], acc);
                wv[t][ci] = acc;
            }
        }

        // ---- B: messages -> wave-private LDS (consumes xj of THIS chunk;
        //         the vmcnt wait here only has gathers older than prev atomics)
#pragma unroll
        for (int ci = 0; ci < 8; ++ci) {
            float x0v = xj0[ci];
            float dotv = (xj1m[0][ci] * sh1a[0] + xj1m[1][ci] * sh1a[1] +
                          xj1m[2][ci] * sh1a[2]) * INV_SQRT3;
            msgL[wave][lane][ci] =
                (wv[0][ci] * x0v * sh.x + wv[1][ci] * dotv) * INV_SQRT2;
#pragma unroll
            for (int m = 0; m < 3; ++m) {
                msgL[wave][lane][8 * (m + 1) + ci] =
                    (wv[2][ci] * x0v * sh1a[m] +
                     wv[3][ci] * xj1m[m][ci] * sh.x) * INV_SQRT2;
            }
        }

        __builtin_amdgcn_sched_barrier(0);

        // ---- C: issue NEXT chunk's gather BEFORE this chunk's atomics ----
        {
            const int cbn = (cb + 1) & 7;   // last iter re-reads chunk 0 (unused)
#pragma unroll
            for (int q = 0; q < 2; ++q) {
                float4 v0 = *reinterpret_cast<const float4*>(xrow + cbn * 8 + 4 * q);
                xj0[4 * q + 0] = v0.x; xj0[4 * q + 1] = v0.y;
                xj0[4 * q + 2] = v0.z; xj0[4 * q + 3] = v0.w;
#pragma unroll
                for (int m = 0; m < 3; ++m) {
                    float4 v1 = *reinterpret_cast<const float4*>(
                        xrow + (m + 1) * 64 + cbn * 8 + 4 * q);
                    xj1m[m][4 * q + 0] = v1.x; xj1m[m][4 * q + 1] = v1.y;
                    xj1m[m][4 * q + 2] = v1.z; xj1m[m][4 * q + 3] = v1.w;
                }
            }
        }

        // pin order: gathers above, atomics below; LDS write->read hazard
        __builtin_amdgcn_sched_barrier(0);
        asm volatile("s_waitcnt lgkmcnt(0)" ::: "memory");
        __builtin_amdgcn_sched_barrier(0);

        // ---- D: coalesced scatter (fire-and-forget atomics) ----
        for (int ep = 0; ep < 32; ++ep) {
            const int eL = 2 * ep + sub;
            const float v = msgL[wave][eL][jj];
            const int eg = eBlockBase + wave * 64 + eL;
            if (eg < E) {
                const int r = recvL[wave][eL];
                atomicAdd(aggScat + (size_t)r * FDIM + cb * 8, v);
            }
        }
        __builtin_amdgcn_sched_barrier(0);
        // msgL reuse safe: DS pipe is in-order per wave (write-after-read).
    }
}

// ---------------- post transform ---------------------------------------------
__global__ void __launch_bounds__(256) post_kernel(
    const float* __restrict__ agg, const float* __restrict__ W0,
    const float* __restrict__ W1, float* __restrict__ out, int nNodes)
{
    const int lane = threadIdx.x & 63;
    const int wave = threadIdx.x >> 6;
    const int waveId = blockIdx.x * 4 + wave;
    const int nWaves = gridDim.x * 4;

    float w0r[64], w1r[64];
#pragma unroll
    for (int c = 0; c < 64; ++c) {
        w0r[c] = W0[c * 64 + lane];
        w1r[c] = W1[c * 64 + lane];
    }

    for (int n = waveId; n < nNodes; n += nWaves) {
        const float* __restrict__ row = agg + (size_t)n * FDIM;
        float a0 = 0.f, a1 = 0.f, a2 = 0.f, a3 = 0.f;
#pragma unroll
        for (int c = 0; c < 64; ++c) {
            a0 = fmaf(row[c],       w0r[c], a0);
            a1 = fmaf(row[64 + c],  w1r[c], a1);
            a2 = fmaf(row[128 + c], w1r[c], a2);
            a3 = fmaf(row[192 + c], w1r[c], a3);
        }
        float4 o4;
        o4.x = a0 * 0.125f;
        o4.y = a1 * 0.125f;
        o4.z = a2 * 0.125f;
        o4.w = a3 * 0.125f;
        *reinterpret_cast<float4*>(out + (size_t)n * FDIM + lane * 4) = o4;
    }
}

extern "C" void kernel_launch(void* const* d_in, const int* in_sizes, int n_in,
                              void* d_out, int out_size, void* d_ws, size_t ws_size,
                              hipStream_t stream) {
    const float* nf     = (const float*)d_in[0];
    const float* sph    = (const float*)d_in[1];
    const float* rb     = (const float*)d_in[2];
    const float* preW0  = (const float*)d_in[3];
    const float* preW1  = (const float*)d_in[4];
    const float* mlpW1  = (const float*)d_in[5];
    const float* mlpW2  = (const float*)d_in[6];
    const float* mlpW3  = (const float*)d_in[7];
    const float* postW0 = (const float*)d_in[8];
    const float* postW1 = (const float*)d_in[9];
    const int*   ei     = (const int*)d_in[10];

    const int N = in_sizes[0] / FDIM;   // 50000
    const int E = in_sizes[1] / 4;      // 800000

    float* xt  = (float*)d_ws;                  // N*256
    float* agg = xt + (size_t)N * FDIM;         // N*256
    float* W1t = agg + (size_t)N * FDIM;        // 512
    float* W2t = W1t + 512;                     // 4096
    float* W3t = W2t + 4096;                    // 16384

    hipMemsetAsync(agg, 0, (size_t)N * FDIM * sizeof(float), stream);

    transpose_w<<<64, 256, 0, stream>>>(mlpW1, mlpW2, mlpW3, W1t, W2t, W3t);
    pre_kernel<<<2048, 256, 0, stream>>>(nf, preW0, preW1, xt, N);
    edge_kernel<<<(E + 255) / 256, 256, 0, stream>>>(
        xt, sph, rb, ei, W1t, W2t, W3t, agg, E);
    post_kernel<<<2048, 256, 0, stream>>>(agg, postW0, postW1, (float*)d_out, N);
}

// Round 7
// 1570.654 us; speedup vs baseline: 1.6226x; 1.6226x over previous
//
#include <hip/hip_runtime.h>

// MACE interaction: N=50000 nodes, E=800000 edges, C=64, R=8, H=64
// Layers 2+3 of the radial MLP on bf16 MFMA (fp32 accum); layer 1, tensor-
// product messages, and the coalesced atomic scatter in fp32 VALU.
// ws (floats): xt N*256 | agg N*256 | W1t 512 | then u16: W2bf 4096 | W3bf 16384
//   W2bf[j*64+k]   = bf16(W2[k][j])                 (row = output col, contiguous k)
//   W3bf[(cb*32 + t*8 + ci)*64 + k] = bf16(W3[k][t*64+cb*8+ci])  (chunk-major cols)

#define FDIM 256
#define INV_SQRT2 0.7071067811865476f
#define INV_SQRT3 0.5773502691896258f

typedef __attribute__((ext_vector_type(8))) short s16x8;   // 8 bf16 = 4 VGPRs
typedef __attribute__((ext_vector_type(4))) float fx4;

__device__ __forceinline__ float silu_f(float x) { return x / (1.0f + __expf(-x)); }

__device__ __forceinline__ unsigned short f2bf(float x) {  // RNE f32->bf16
    unsigned int u = __float_as_uint(x);
    u += 0x7FFFu + ((u >> 16) & 1u);
    return (unsigned short)(u >> 16);
}

// byte-offset XOR swizzle for 128B-pitch LDS rows (kills bank conflicts for
// both column-slice fragment reads and per-lane row reads). Bits 4..6 only,
// so 16B-aligned b128 accesses stay aligned.
__device__ __forceinline__ int swz(int row) {
    return ((row & 7) ^ ((row >> 3) & 7)) << 4;
}

// ---------------- weight prep: transpose + bf16 quantize (trivial) ----------
__global__ void __launch_bounds__(256) transpose_w(
    const float* __restrict__ W1, const float* __restrict__ W2,
    const float* __restrict__ W3, float* __restrict__ W1t,
    unsigned short* __restrict__ W2bf, unsigned short* __restrict__ W3bf)
{
    int i = blockIdx.x * 256 + threadIdx.x;
    if (i < 512)  { int r = i >> 6, k = i & 63; W1t[k * 8 + r] = W1[i]; }
    if (i < 4096) { int j = i >> 6, k = i & 63; W2bf[i] = f2bf(W2[k * 64 + j]); }
    if (i < 16384) {
        int col = i >> 6, k = i & 63;
        int cb = col >> 5, r32 = col & 31, t = r32 >> 3, ci = r32 & 7;
        W3bf[i] = f2bf(W3[k * 256 + t * 64 + cb * 8 + ci]);
    }
}

// ---------------- pre transform: x0 = nf@W0/8 ; x1[:,m] = x1m@W1/8 -----------
__global__ void __launch_bounds__(256) pre_kernel(
    const float* __restrict__ nf, const float* __restrict__ W0,
    const float* __restrict__ W1, float* __restrict__ xt, int nNodes)
{
    const int lane = threadIdx.x & 63;
    const int wave = threadIdx.x >> 6;
    const int waveId = blockIdx.x * 4 + wave;
    const int nWaves = gridDim.x * 4;

    float w0r[64], w1r[64];
#pragma unroll
    for (int c = 0; c < 64; ++c) {
        w0r[c] = W0[c * 64 + lane];
        w1r[c] = W1[c * 64 + lane];
    }

    for (int n = waveId; n < nNodes; n += nWaves) {
        const float* __restrict__ row = nf + (size_t)n * FDIM;
        float a0 = 0.f, a1 = 0.f, a2 = 0.f, a3 = 0.f;
#pragma unroll
        for (int c = 0; c < 64; ++c) {
            float x0  = row[c];
            float xm0 = row[64 + 3 * c + 0];
            float xm1 = row[64 + 3 * c + 1];
            float xm2 = row[64 + 3 * c + 2];
            a0 = fmaf(x0,  w0r[c], a0);
            a1 = fmaf(xm0, w1r[c], a1);
            a2 = fmaf(xm1, w1r[c], a2);
            a3 = fmaf(xm2, w1r[c], a3);
        }
        float* o = xt + (size_t)n * FDIM;
        o[lane]       = a0 * 0.125f;
        o[64 + lane]  = a1 * 0.125f;
        o[128 + lane] = a2 * 0.125f;
        o[192 + lane] = a3 * 0.125f;
    }
}

// ---------------- fused edge kernel (MFMA MLP + messages + atomic scatter) ---
// Wave = 64 edges. All LDS wave-private; no __syncthreads in the kernel.
__global__ void __launch_bounds__(256) edge_kernel(
    const float* __restrict__ xt, const float* __restrict__ sph,
    const float* __restrict__ rb, const int* __restrict__ ei,
    const float* __restrict__ W1t, const unsigned short* __restrict__ W2bf,
    const unsigned short* __restrict__ W3bf, float* __restrict__ agg, int E)
{
    const int tid  = threadIdx.x;
    const int lane = tid & 63;
    const int wave = tid >> 6;
    const int eBase = blockIdx.x * 256 + wave * 64;
    const int e = eBase + lane;
    const int eSafe = (e < E) ? e : (E - 1);

    __shared__ __align__(16) char sbufAll[4][8192];   // 64 rows x 128B per wave
    __shared__ int recvL[4][64];
    char* const sbuf = sbufAll[wave];

    // ---------- layer 1: h1 = silu(rb @ W1), fp32 VALU ----------
    const float4 rq0 = *reinterpret_cast<const float4*>(rb + (size_t)eSafe * 8);
    const float4 rq1 = *reinterpret_cast<const float4*>(rb + (size_t)eSafe * 8 + 4);
    const float rbv[8] = {rq0.x, rq0.y, rq0.z, rq0.w, rq1.x, rq1.y, rq1.z, rq1.w};

    float h1[64];
#pragma unroll
    for (int k = 0; k < 64; ++k) {
        float acc = 0.f;
#pragma unroll
        for (int r = 0; r < 8; ++r) acc = fmaf(rbv[r], W1t[k * 8 + r], acc);
        h1[k] = silu_f(acc);
    }

    // h1 -> bf16 -> own LDS row (8x b128, swizzled)
#pragma unroll
    for (int q = 0; q < 8; ++q) {
        s16x8 v;
#pragma unroll
        for (int t = 0; t < 8; ++t) v[t] = (short)f2bf(h1[q * 8 + t]);
        *reinterpret_cast<s16x8*>(sbuf + lane * 128 + ((q * 16) ^ swz(lane))) = v;
    }

    const float4 shv = *reinterpret_cast<const float4*>(sph + (size_t)eSafe * 4);
    const float sh1a[3] = {shv.y, shv.z, shv.w};
    recvL[wave][lane] = ei[eSafe];
    const int send = ei[E + eSafe];
    const float* __restrict__ xrow = xt + (size_t)send * FDIM;

    const int l15 = lane & 15;
    const int g4  = lane >> 4;

    // ---------- W2 B-fragments (global bf16, loaded once) ----------
    s16x8 bW2[4][2];
#pragma unroll
    for (int n = 0; n < 4; ++n)
#pragma unroll
        for (int kk = 0; kk < 2; ++kk)
            bW2[n][kk] = *reinterpret_cast<const s16x8*>(
                W2bf + (n * 16 + l15) * 64 + kk * 32 + g4 * 8);

    // ---------- h1 A-fragments ----------
    s16x8 aH[4][2];
#pragma unroll
    for (int m = 0; m < 4; ++m)
#pragma unroll
        for (int kk = 0; kk < 2; ++kk) {
            int row = m * 16 + l15;
            aH[m][kk] = *reinterpret_cast<const s16x8*>(
                sbuf + row * 128 + ((kk * 64 + g4 * 16) ^ swz(row)));
        }

    // ---------- layer 2: h2 = silu(h1 @ W2), 32 MFMA ----------
    fx4 acc2[4][4];
#pragma unroll
    for (int m = 0; m < 4; ++m)
#pragma unroll
        for (int n = 0; n < 4; ++n) {
            fx4 z = {0.f, 0.f, 0.f, 0.f};
            acc2[m][n] = z;
        }
#pragma unroll
    for (int kk = 0; kk < 2; ++kk)
#pragma unroll
        for (int m = 0; m < 4; ++m)
#pragma unroll
            for (int n = 0; n < 4; ++n)
                acc2[m][n] = __builtin_amdgcn_mfma_f32_16x16x32_bf16(
                    aH[m][kk], bW2[n][kk], acc2[m][n], 0, 0, 0);

    // epilogue: silu -> bf16 -> LDS rows [edge][j] (b16 scattered writes)
#pragma unroll
    for (int m = 0; m < 4; ++m)
#pragma unroll
        for (int n = 0; n < 4; ++n)
#pragma unroll
            for (int r = 0; r < 4; ++r) {
                int edge = m * 16 + g4 * 4 + r;
                int j = n * 16 + l15;
                *reinterpret_cast<unsigned short*>(
                    sbuf + edge * 128 + ((2 * j) ^ swz(edge))) =
                    f2bf(silu_f(acc2[m][n][r]));
            }

    // ---------- h2 A-fragments (kept in VGPRs for all 8 chunks) ----------
    s16x8 aH2[4][2];
#pragma unroll
    for (int m = 0; m < 4; ++m)
#pragma unroll
        for (int kk = 0; kk < 2; ++kk) {
            int row = m * 16 + l15;
            aH2[m][kk] = *reinterpret_cast<const s16x8*>(
                sbuf + row * 128 + ((kk * 64 + g4 * 16) ^ swz(row)));
        }

    // scatter constants
    const int jj  = lane & 31;
    const int tt  = jj >> 3;
    const int ci2 = jj & 7;
    const int sub = lane >> 5;
    float* const aggScat = agg + tt * 64 + ci2;

    for (int cb = 0; cb < 8; ++cb) {
        // xj gather for this chunk (issues early, hides under MFMA)
        float xj0[8], xj1m[3][8];
#pragma unroll
        for (int q = 0; q < 2; ++q) {
            float4 v0 = *reinterpret_cast<const float4*>(xrow + cb * 8 + 4 * q);
            xj0[4*q+0]=v0.x; xj0[4*q+1]=v0.y; xj0[4*q+2]=v0.z; xj0[4*q+3]=v0.w;
#pragma unroll
            for (int m = 0; m < 3; ++m) {
                float4 v1 = *reinterpret_cast<const float4*>(
                    xrow + (m + 1) * 64 + cb * 8 + 4 * q);
                xj1m[m][4*q+0]=v1.x; xj1m[m][4*q+1]=v1.y;
                xj1m[m][4*q+2]=v1.z; xj1m[m][4*q+3]=v1.w;
            }
        }

        // W3 B-fragments for this chunk (32 contiguous cols = 2 n-tiles)
        s16x8 bW3[2][2];
#pragma unroll
        for (int n2 = 0; n2 < 2; ++n2)
#pragma unroll
            for (int kk = 0; kk < 2; ++kk)
                bW3[n2][kk] = *reinterpret_cast<const s16x8*>(
                    W3bf + (cb * 32 + n2 * 16 + l15) * 64 + kk * 32 + g4 * 8);

        // layer 3 chunk: (64 x 64) @ (64 x 32), 16 MFMA
        fx4 accw[4][2];
#pragma unroll
        for (int m = 0; m < 4; ++m)
#pragma unroll
            for (int n2 = 0; n2 < 2; ++n2) {
                fx4 z = {0.f, 0.f, 0.f, 0.f};
                accw[m][n2] = z;
            }
#pragma unroll
        for (int kk = 0; kk < 2; ++kk)
#pragma unroll
            for (int m = 0; m < 4; ++m)
#pragma unroll
                for (int n2 = 0; n2 < 2; ++n2)
                    accw[m][n2] = __builtin_amdgcn_mfma_f32_16x16x32_bf16(
                        aH2[m][kk], bW3[n2][kk], accw[m][n2], 0, 0, 0);

        // w (f32) -> LDS rows [edge][col32]; col32 = t*8+ci by W3bf permutation
#pragma unroll
        for (int m = 0; m < 4; ++m)
#pragma unroll
            for (int n2 = 0; n2 < 2; ++n2)
#pragma unroll
                for (int r = 0; r < 4; ++r) {
                    int edge = m * 16 + g4 * 4 + r;
                    int c32 = n2 * 16 + l15;
                    *reinterpret_cast<float*>(
                        sbuf + edge * 128 + ((c32 * 4) ^ swz(edge))) = accw[m][n2][r];
                }

        // read own row's w: wv[t][ci]  (lane = edge)
        float wv[4][8];
#pragma unroll
        for (int t = 0; t < 4; ++t)
#pragma unroll
            for (int q = 0; q < 2; ++q) {
                fx4 v = *reinterpret_cast<const fx4*>(
                    sbuf + lane * 128 + ((t * 32 + q * 16) ^ swz(lane)));
                wv[t][q*4+0]=v.x; wv[t][q*4+1]=v.y; wv[t][q*4+2]=v.z; wv[t][q*4+3]=v.w;
            }

        // messages -> own LDS row (overwrites own w AFTER reading it)
        float msg[32];
#pragma unroll
        for (int ci = 0; ci < 8; ++ci) {
            float x0v = xj0[ci];
            float dotv = (xj1m[0][ci]*sh1a[0] + xj1m[1][ci]*sh1a[1] +
                          xj1m[2][ci]*sh1a[2]) * INV_SQRT3;
            msg[ci] = (wv[0][ci]*x0v*shv.x + wv[1][ci]*dotv) * INV_SQRT2;
#pragma unroll
            for (int m = 0; m < 3; ++m)
                msg[(m+1)*8+ci] = (wv[2][ci]*x0v*sh1a[m] +
                                   wv[3][ci]*xj1m[m][ci]*shv.x) * INV_SQRT2;
        }
#pragma unroll
        for (int q = 0; q < 8; ++q) {
            fx4 v = {msg[q*4+0], msg[q*4+1], msg[q*4+2], msg[q*4+3]};
            *reinterpret_cast<fx4*>(sbuf + lane * 128 + ((q * 16) ^ swz(lane))) = v;
        }

        // coalesced atomic scatter: 2 edges x 32 consecutive floats per instr
        for (int ep = 0; ep < 32; ++ep) {
            const int eL = 2 * ep + sub;
            const float v = *reinterpret_cast<const float*>(
                sbuf + eL * 128 + ((jj * 4) ^ swz(eL)));
            const int eg = eBase + eL;
            if (eg < E)
                atomicAdd(aggScat + (size_t)recvL[wave][eL] * FDIM + cb * 8, v);
        }
    }
}

// ---------------- post transform ---------------------------------------------
__global__ void __launch_bounds__(256) post_kernel(
    const float* __restrict__ agg, const float* __restrict__ W0,
    const float* __restrict__ W1, float* __restrict__ out, int nNodes)
{
    const int lane = threadIdx.x & 63;
    const int wave = threadIdx.x >> 6;
    const int waveId = blockIdx.x * 4 + wave;
    const int nWaves = gridDim.x * 4;

    float w0r[64], w1r[64];
#pragma unroll
    for (int c = 0; c < 64; ++c) {
        w0r[c] = W0[c * 64 + lane];
        w1r[c] = W1[c * 64 + lane];
    }

    for (int n = waveId; n < nNodes; n += nWaves) {
        const float* __restrict__ row = agg + (size_t)n * FDIM;
        float a0 = 0.f, a1 = 0.f, a2 = 0.f, a3 = 0.f;
#pragma unroll
        for (int c = 0; c < 64; ++c) {
            a0 = fmaf(row[c],       w0r[c], a0);
            a1 = fmaf(row[64 + c],  w1r[c], a1);
            a2 = fmaf(row[128 + c], w1r[c], a2);
            a3 = fmaf(row[192 + c], w1r[c], a3);
        }
        float4 o4;
        o4.x = a0 * 0.125f;
        o4.y = a1 * 0.125f;
        o4.z = a2 * 0.125f;
        o4.w = a3 * 0.125f;
        *reinterpret_cast<float4*>(out + (size_t)n * FDIM + lane * 4) = o4;
    }
}

extern "C" void kernel_launch(void* const* d_in, const int* in_sizes, int n_in,
                              void* d_out, int out_size, void* d_ws, size_t ws_size,
                              hipStream_t stream) {
    const float* nf     = (const float*)d_in[0];
    const float* sph    = (const float*)d_in[1];
    const float* rb     = (const float*)d_in[2];
    const float* preW0  = (const float*)d_in[3];
    const float* preW1  = (const float*)d_in[4];
    const float* mlpW1  = (const float*)d_in[5];
    const float* mlpW2  = (const float*)d_in[6];
    const float* mlpW3  = (const float*)d_in[7];
    const float* postW0 = (const float*)d_in[8];
    const float* postW1 = (const float*)d_in[9];
    const int*   ei     = (const int*)d_in[10];

    const int N = in_sizes[0] / FDIM;   // 50000
    const int E = in_sizes[1] / 4;      // 800000

    float* xt  = (float*)d_ws;                    // N*256 f32
    float* agg = xt + (size_t)N * FDIM;           // N*256 f32
    float* W1t = agg + (size_t)N * FDIM;          // 512 f32
    unsigned short* W2bf = (unsigned short*)(W1t + 512);   // 4096 u16
    unsigned short* W3bf = W2bf + 4096;                    // 16384 u16

    hipMemsetAsync(agg, 0, (size_t)N * FDIM * sizeof(float), stream);

    transpose_w<<<64, 256, 0, stream>>>(mlpW1, mlpW2, mlpW3, W1t, W2bf, W3bf);
    pre_kernel<<<2048, 256, 0, stream>>>(nf, preW0, preW1, xt, N);
    edge_kernel<<<(E + 255) / 256, 256, 0, stream>>>(
        xt, sph, rb, ei, W1t, W2bf, W3bf, agg, E);
    post_kernel<<<2048, 256, 0, stream>>>(agg, postW0, postW1, (float*)d_out, N);
}

// Round 8
// 965.637 us; speedup vs baseline: 2.6392x; 1.6265x over previous
//
#include <hip/hip_runtime.h>

// MACE interaction: N=50000 nodes, E=800000 edges, C=64, R=8, H=64
// R8: counting-sort edges by recv; edge kernel walks sorted order and does a
// run-segmented pre-reduction before the atomic scatter (atomics ~7x fewer).
// ws: xt N*256 f32 | agg N*256 f32 | W1t 512 f32 | W2bf 4096 u16 | W3bf 16384 u16
//     | cnt N i32 | cursor N i32 | perm E i32     (~106 MB total)

#define FDIM 256
#define INV_SQRT2 0.7071067811865476f
#define INV_SQRT3 0.5773502691896258f

typedef __attribute__((ext_vector_type(8))) short s16x8;
typedef __attribute__((ext_vector_type(4))) float fx4;

__device__ __forceinline__ float silu_f(float x) { return x / (1.0f + __expf(-x)); }

__device__ __forceinline__ unsigned short f2bf(float x) {
    unsigned int u = __float_as_uint(x);
    u += 0x7FFFu + ((u >> 16) & 1u);
    return (unsigned short)(u >> 16);
}

__device__ __forceinline__ int swz(int row) {
    return ((row & 7) ^ ((row >> 3) & 7)) << 4;
}

// ---------------- weight prep ------------------------------------------------
__global__ void __launch_bounds__(256) transpose_w(
    const float* __restrict__ W1, const float* __restrict__ W2,
    const float* __restrict__ W3, float* __restrict__ W1t,
    unsigned short* __restrict__ W2bf, unsigned short* __restrict__ W3bf)
{
    int i = blockIdx.x * 256 + threadIdx.x;
    if (i < 512)  { int r = i >> 6, k = i & 63; W1t[k * 8 + r] = W1[i]; }
    if (i < 4096) { int j = i >> 6, k = i & 63; W2bf[i] = f2bf(W2[k * 64 + j]); }
    if (i < 16384) {
        int col = i >> 6, k = i & 63;
        int cb = col >> 5, r32 = col & 31, t = r32 >> 3, ci = r32 & 7;
        W3bf[i] = f2bf(W3[k * 256 + t * 64 + cb * 8 + ci]);
    }
}

// ---------------- counting sort by recv ---------------------------------------
__global__ void __launch_bounds__(256) hist_kernel(
    const int* __restrict__ ei, int* __restrict__ cnt, int E)
{
    int i = blockIdx.x * 256 + threadIdx.x;
    if (i < E) atomicAdd(&cnt[ei[i]], 1);
}

__global__ void __launch_bounds__(1024) scan_kernel(
    const int* __restrict__ cnt, int* __restrict__ cursor, int nBins)
{
    __shared__ int part[1024];
    const int t = threadIdx.x;
    const int per = (nBins + 1023) / 1024;
    const int lo = t * per;
    const int hi = (lo + per < nBins) ? lo + per : nBins;

    int s = 0;
    for (int i = lo; i < hi; ++i) s += cnt[i];
    part[t] = s;
    __syncthreads();

    for (int off = 1; off < 1024; off <<= 1) {
        int v = part[t];
        int add = (t >= off) ? part[t - off] : 0;
        __syncthreads();
        part[t] = v + add;
        __syncthreads();
    }

    int run = part[t] - s;   // exclusive base for this thread's bins
    for (int i = lo; i < hi; ++i) {
        cursor[i] = run;
        run += cnt[i];
    }
}

__global__ void __launch_bounds__(256) scatter_perm_kernel(
    const int* __restrict__ ei, int* __restrict__ cursor,
    int* __restrict__ perm, int E)
{
    int i = blockIdx.x * 256 + threadIdx.x;
    if (i < E) {
        int p = atomicAdd(&cursor[ei[i]], 1);
        perm[p] = i;
    }
}

// ---------------- pre transform ----------------------------------------------
__global__ void __launch_bounds__(256) pre_kernel(
    const float* __restrict__ nf, const float* __restrict__ W0,
    const float* __restrict__ W1, float* __restrict__ xt, int nNodes)
{
    const int lane = threadIdx.x & 63;
    const int wave = threadIdx.x >> 6;
    const int waveId = blockIdx.x * 4 + wave;
    const int nWaves = gridDim.x * 4;

    float w0r[64], w1r[64];
#pragma unroll
    for (int c = 0; c < 64; ++c) {
        w0r[c] = W0[c * 64 + lane];
        w1r[c] = W1[c * 64 + lane];
    }

    for (int n = waveId; n < nNodes; n += nWaves) {
        const float* __restrict__ row = nf + (size_t)n * FDIM;
        float a0 = 0.f, a1 = 0.f, a2 = 0.f, a3 = 0.f;
#pragma unroll
        for (int c = 0; c < 64; ++c) {
            float x0  = row[c];
            float xm0 = row[64 + 3 * c + 0];
            float xm1 = row[64 + 3 * c + 1];
            float xm2 = row[64 + 3 * c + 2];
            a0 = fmaf(x0,  w0r[c], a0);
            a1 = fmaf(xm0, w1r[c], a1);
            a2 = fmaf(xm1, w1r[c], a2);
            a3 = fmaf(xm2, w1r[c], a3);
        }
        float* o = xt + (size_t)n * FDIM;
        o[lane]       = a0 * 0.125f;
        o[64 + lane]  = a1 * 0.125f;
        o[128 + lane] = a2 * 0.125f;
        o[192 + lane] = a3 * 0.125f;
    }
}

// ---------------- fused edge kernel (sorted order, MFMA MLP, seg-reduced scatter)
__global__ void __launch_bounds__(256) edge_kernel(
    const float* __restrict__ xt, const float* __restrict__ sph,
    const float* __restrict__ rb, const int* __restrict__ ei,
    const int* __restrict__ perm,
    const float* __restrict__ W1t, const unsigned short* __restrict__ W2bf,
    const unsigned short* __restrict__ W3bf, float* __restrict__ agg, int E)
{
    const int tid  = threadIdx.x;
    const int lane = tid & 63;
    const int wave = tid >> 6;
    const int eBase = blockIdx.x * 256 + wave * 64;   // sorted position base
    const int idx = eBase + lane;
    const int idxSafe = (idx < E) ? idx : (E - 1);
    const int pe = perm[idxSafe];                     // original edge id

    __shared__ __align__(16) char sbufAll[4][8192];
    __shared__ int recvL[4][64];
    char* const sbuf = sbufAll[wave];

    // ---------- layer 1: h1 = silu(rb @ W1), fp32 VALU ----------
    const float4 rq0 = *reinterpret_cast<const float4*>(rb + (size_t)pe * 8);
    const float4 rq1 = *reinterpret_cast<const float4*>(rb + (size_t)pe * 8 + 4);
    const float rbv[8] = {rq0.x, rq0.y, rq0.z, rq0.w, rq1.x, rq1.y, rq1.z, rq1.w};

    float h1[64];
#pragma unroll
    for (int k = 0; k < 64; ++k) {
        float acc = 0.f;
#pragma unroll
        for (int r = 0; r < 8; ++r) acc = fmaf(rbv[r], W1t[k * 8 + r], acc);
        h1[k] = silu_f(acc);
    }

#pragma unroll
    for (int q = 0; q < 8; ++q) {
        s16x8 v;
#pragma unroll
        for (int t = 0; t < 8; ++t) v[t] = (short)f2bf(h1[q * 8 + t]);
        *reinterpret_cast<s16x8*>(sbuf + lane * 128 + ((q * 16) ^ swz(lane))) = v;
    }

    const float4 shv = *reinterpret_cast<const float4*>(sph + (size_t)pe * 4);
    const float sh1a[3] = {shv.y, shv.z, shv.w};
    recvL[wave][lane] = ei[pe];
    const int send = ei[E + pe];
    const float* __restrict__ xrow = xt + (size_t)send * FDIM;

    const int l15 = lane & 15;
    const int g4  = lane >> 4;

    // ---------- W2 B-fragments ----------
    s16x8 bW2[4][2];
#pragma unroll
    for (int n = 0; n < 4; ++n)
#pragma unroll
        for (int kk = 0; kk < 2; ++kk)
            bW2[n][kk] = *reinterpret_cast<const s16x8*>(
                W2bf + (n * 16 + l15) * 64 + kk * 32 + g4 * 8);

    // ---------- h1 A-fragments ----------
    s16x8 aH[4][2];
#pragma unroll
    for (int m = 0; m < 4; ++m)
#pragma unroll
        for (int kk = 0; kk < 2; ++kk) {
            int row = m * 16 + l15;
            aH[m][kk] = *reinterpret_cast<const s16x8*>(
                sbuf + row * 128 + ((kk * 64 + g4 * 16) ^ swz(row)));
        }

    // ---------- layer 2: 32 MFMA ----------
    fx4 acc2[4][4];
#pragma unroll
    for (int m = 0; m < 4; ++m)
#pragma unroll
        for (int n = 0; n < 4; ++n) {
            fx4 z = {0.f, 0.f, 0.f, 0.f};
            acc2[m][n] = z;
        }
#pragma unroll
    for (int kk = 0; kk < 2; ++kk)
#pragma unroll
        for (int m = 0; m < 4; ++m)
#pragma unroll
            for (int n = 0; n < 4; ++n)
                acc2[m][n] = __builtin_amdgcn_mfma_f32_16x16x32_bf16(
                    aH[m][kk], bW2[n][kk], acc2[m][n], 0, 0, 0);

#pragma unroll
    for (int m = 0; m < 4; ++m)
#pragma unroll
        for (int n = 0; n < 4; ++n)
#pragma unroll
            for (int r = 0; r < 4; ++r) {
                int edge = m * 16 + g4 * 4 + r;
                int j = n * 16 + l15;
                *reinterpret_cast<unsigned short*>(
                    sbuf + edge * 128 + ((2 * j) ^ swz(edge))) =
                    f2bf(silu_f(acc2[m][n][r]));
            }

    // ---------- h2 A-fragments ----------
    s16x8 aH2[4][2];
#pragma unroll
    for (int m = 0; m < 4; ++m)
#pragma unroll
        for (int kk = 0; kk < 2; ++kk) {
            int row = m * 16 + l15;
            aH2[m][kk] = *reinterpret_cast<const s16x8*>(
                sbuf + row * 128 + ((kk * 64 + g4 * 16) ^ swz(row)));
        }

    // scatter constants
    const int jj  = lane & 31;
    const int tt  = jj >> 3;
    const int ci2 = jj & 7;
    const int sub = lane >> 5;
    float* const aggScat = agg + tt * 64 + ci2;

    for (int cb = 0; cb < 8; ++cb) {
        // xj gather (early issue)
        float xj0[8], xj1m[3][8];
#pragma unroll
        for (int q = 0; q < 2; ++q) {
            float4 v0 = *reinterpret_cast<const float4*>(xrow + cb * 8 + 4 * q);
            xj0[4*q+0]=v0.x; xj0[4*q+1]=v0.y; xj0[4*q+2]=v0.z; xj0[4*q+3]=v0.w;
#pragma unroll
            for (int m = 0; m < 3; ++m) {
                float4 v1 = *reinterpret_cast<const float4*>(
                    xrow + (m + 1) * 64 + cb * 8 + 4 * q);
                xj1m[m][4*q+0]=v1.x; xj1m[m][4*q+1]=v1.y;
                xj1m[m][4*q+2]=v1.z; xj1m[m][4*q+3]=v1.w;
            }
        }

        // W3 B-fragments for this chunk
        s16x8 bW3[2][2];
#pragma unroll
        for (int n2 = 0; n2 < 2; ++n2)
#pragma unroll
            for (int kk = 0; kk < 2; ++kk)
                bW3[n2][kk] = *reinterpret_cast<const s16x8*>(
                    W3bf + (cb * 32 + n2 * 16 + l15) * 64 + kk * 32 + g4 * 8);

        // layer 3 chunk: 16 MFMA
        fx4 accw[4][2];
#pragma unroll
        for (int m = 0; m < 4; ++m)
#pragma unroll
            for (int n2 = 0; n2 < 2; ++n2) {
                fx4 z = {0.f, 0.f, 0.f, 0.f};
                accw[m][n2] = z;
            }
#pragma unroll
        for (int kk = 0; kk < 2; ++kk)
#pragma unroll
            for (int m = 0; m < 4; ++m)
#pragma unroll
                for (int n2 = 0; n2 < 2; ++n2)
                    accw[m][n2] = __builtin_amdgcn_mfma_f32_16x16x32_bf16(
                        aH2[m][kk], bW3[n2][kk], accw[m][n2], 0, 0, 0);

        // w -> LDS rows
#pragma unroll
        for (int m = 0; m < 4; ++m)
#pragma unroll
            for (int n2 = 0; n2 < 2; ++n2)
#pragma unroll
                for (int r = 0; r < 4; ++r) {
                    int edge = m * 16 + g4 * 4 + r;
                    int c32 = n2 * 16 + l15;
                    *reinterpret_cast<float*>(
                        sbuf + edge * 128 + ((c32 * 4) ^ swz(edge))) = accw[m][n2][r];
                }

        // own row's w
        float wv[4][8];
#pragma unroll
        for (int t = 0; t < 4; ++t)
#pragma unroll
            for (int q = 0; q < 2; ++q) {
                fx4 v = *reinterpret_cast<const fx4*>(
                    sbuf + lane * 128 + ((t * 32 + q * 16) ^ swz(lane)));
                wv[t][q*4+0]=v.x; wv[t][q*4+1]=v.y; wv[t][q*4+2]=v.z; wv[t][q*4+3]=v.w;
            }

        // messages -> own LDS row
        float msg[32];
#pragma unroll
        for (int ci = 0; ci < 8; ++ci) {
            float x0v = xj0[ci];
            float dotv = (xj1m[0][ci]*sh1a[0] + xj1m[1][ci]*sh1a[1] +
                          xj1m[2][ci]*sh1a[2]) * INV_SQRT3;
            msg[ci] = (wv[0][ci]*x0v*shv.x + wv[1][ci]*dotv) * INV_SQRT2;
#pragma unroll
            for (int m = 0; m < 3; ++m)
                msg[(m+1)*8+ci] = (wv[2][ci]*x0v*sh1a[m] +
                                   wv[3][ci]*xj1m[m][ci]*shv.x) * INV_SQRT2;
        }
#pragma unroll
        for (int q = 0; q < 8; ++q) {
            fx4 v = {msg[q*4+0], msg[q*4+1], msg[q*4+2], msg[q*4+3]};
            *reinterpret_cast<fx4*>(sbuf + lane * 128 + ((q * 16) ^ swz(lane))) = v;
        }

        // ---- run-segmented coalesced scatter (recv sorted within wave) ----
        {
            int rprev = recvL[wave][sub];
            float acc = 0.f;
            for (int ep = 0; ep < 32; ++ep) {
                const int eL = 2 * ep + sub;
                const int eg = eBase + eL;
                float v = *reinterpret_cast<const float*>(
                    sbuf + eL * 128 + ((jj * 4) ^ swz(eL)));
                if (eg >= E) v = 0.f;
                const int r = recvL[wave][eL];
                if (r != rprev) {
                    atomicAdd(aggScat + (size_t)rprev * FDIM + cb * 8, acc);
                    acc = 0.f;
                    rprev = r;
                }
                acc += v;
            }
            atomicAdd(aggScat + (size_t)rprev * FDIM + cb * 8, acc);
        }
    }
}

// ---------------- post transform ---------------------------------------------
__global__ void __launch_bounds__(256) post_kernel(
    const float* __restrict__ agg, const float* __restrict__ W0,
    const float* __restrict__ W1, float* __restrict__ out, int nNodes)
{
    const int lane = threadIdx.x & 63;
    const int wave = threadIdx.x >> 6;
    const int waveId = blockIdx.x * 4 + wave;
    const int nWaves = gridDim.x * 4;

    float w0r[64], w1r[64];
#pragma unroll
    for (int c = 0; c < 64; ++c) {
        w0r[c] = W0[c * 64 + lane];
        w1r[c] = W1[c * 64 + lane];
    }

    for (int n = waveId; n < nNodes; n += nWaves) {
        const float* __restrict__ row = agg + (size_t)n * FDIM;
        float a0 = 0.f, a1 = 0.f, a2 = 0.f, a3 = 0.f;
#pragma unroll
        for (int c = 0; c < 64; ++c) {
            a0 = fmaf(row[c],       w0r[c], a0);
            a1 = fmaf(row[64 + c],  w1r[c], a1);
            a2 = fmaf(row[128 + c], w1r[c], a2);
            a3 = fmaf(row[192 + c], w1r[c], a3);
        }
        float4 o4;
        o4.x = a0 * 0.125f;
        o4.y = a1 * 0.125f;
        o4.z = a2 * 0.125f;
        o4.w = a3 * 0.125f;
        *reinterpret_cast<float4*>(out + (size_t)n * FDIM + lane * 4) = o4;
    }
}

extern "C" void kernel_launch(void* const* d_in, const int* in_sizes, int n_in,
                              void* d_out, int out_size, void* d_ws, size_t ws_size,
                              hipStream_t stream) {
    const float* nf     = (const float*)d_in[0];
    const float* sph    = (const float*)d_in[1];
    const float* rb     = (const float*)d_in[2];
    const float* preW0  = (const float*)d_in[3];
    const float* preW1  = (const float*)d_in[4];
    const float* mlpW1  = (const float*)d_in[5];
    const float* mlpW2  = (const float*)d_in[6];
    const float* mlpW3  = (const float*)d_in[7];
    const float* postW0 = (const float*)d_in[8];
    const float* postW1 = (const float*)d_in[9];
    const int*   ei     = (const int*)d_in[10];

    const int N = in_sizes[0] / FDIM;   // 50000
    const int E = in_sizes[1] / 4;      // 800000

    float* xt  = (float*)d_ws;                    // N*256 f32
    float* agg = xt + (size_t)N * FDIM;           // N*256 f32
    float* W1t = agg + (size_t)N * FDIM;          // 512 f32
    unsigned short* W2bf = (unsigned short*)(W1t + 512);   // 4096 u16
    unsigned short* W3bf = W2bf + 4096;                    // 16384 u16
    int* cnt    = (int*)(W3bf + 16384);           // N i32
    int* cursor = cnt + N;                        // N i32
    int* perm   = cursor + N;                     // E i32

    hipMemsetAsync(agg, 0, (size_t)N * FDIM * sizeof(float), stream);
    hipMemsetAsync(cnt, 0, (size_t)N * sizeof(int), stream);

    transpose_w<<<64, 256, 0, stream>>>(mlpW1, mlpW2, mlpW3, W1t, W2bf, W3bf);
    pre_kernel<<<2048, 256, 0, stream>>>(nf, preW0, preW1, xt, N);
    hist_kernel<<<(E + 255) / 256, 256, 0, stream>>>(ei, cnt, E);
    scan_kernel<<<1, 1024, 0, stream>>>(cnt, cursor, N);
    scatter_perm_kernel<<<(E + 255) / 256, 256, 0, stream>>>(ei, cursor, perm, E);
    edge_kernel<<<(E + 255) / 256, 256, 0, stream>>>(
        xt, sph, rb, ei, perm, W1t, W2bf, W3bf, agg, E);
    post_kernel<<<2048, 256, 0, stream>>>(agg, postW0, postW1, (float*)d_out, N);
}